// Round 5
// baseline (3693.207 us; speedup 1.0000x reference)
//
#include <hip/hip_runtime.h>
#include <math.h>

typedef unsigned short u16;
typedef __bf16 bf16x8 __attribute__((ext_vector_type(8)));
typedef float f32x4 __attribute__((ext_vector_type(4)));

#define MROWS 12608   // B*N = 64*197
#define NSEQ  197
#define NHEAD 12
#define DMODEL 768

__device__ __forceinline__ u16 f2bf(float f) {
    unsigned u = __float_as_uint(f);
    u += 0x7FFFu + ((u >> 16) & 1u);   // RNE
    return (u16)(u >> 16);
}
__device__ __forceinline__ float bf2f(u16 v) { return __uint_as_float(((unsigned)v) << 16); }

// build a bf16x8 A/B fragment from 8 consecutive fp32 values
__device__ __forceinline__ bf16x8 cvt8(const float* p) {
    float4 a = *(const float4*)p;
    float4 b = *(const float4*)(p + 4);
    union { bf16x8 v; u16 s[8]; } t;
    t.s[0] = f2bf(a.x); t.s[1] = f2bf(a.y); t.s[2] = f2bf(a.z); t.s[3] = f2bf(a.w);
    t.s[4] = f2bf(b.x); t.s[5] = f2bf(b.y); t.s[6] = f2bf(b.z); t.s[7] = f2bf(b.w);
    return t.v;
}

// ---------------- layernorm: fp32 in -> bf16 out, one wave per row ----------
__global__ __launch_bounds__(256) void ln_rows(const float* x,
                                               const float* g,
                                               const float* bta,
                                               u16* o, int Mr) {
    int w = threadIdx.x >> 6, lane = threadIdx.x & 63;
    int row = blockIdx.x * 4 + w;
    if (row >= Mr) return;
    const float* xr = x + (size_t)row * DMODEL;
    float vals[12];
    for (int i = 0; i < 6; ++i) {
        float2 xx = *(const float2*)(xr + i * 128 + lane * 2);
        vals[2 * i] = xx.x; vals[2 * i + 1] = xx.y;
    }
    float s = 0.f;
    for (int i = 0; i < 12; ++i) s += vals[i];
    for (int off = 1; off < 64; off <<= 1) s += __shfl_xor(s, off, 64);
    float mu = s * (1.f / 768.f);
    float v2 = 0.f;
    for (int i = 0; i < 12; ++i) { float d = vals[i] - mu; v2 += d * d; }
    for (int off = 1; off < 64; off <<= 1) v2 += __shfl_xor(v2, off, 64);
    float rstd = rsqrtf(v2 * (1.f / 768.f) + 1e-5f);
    u16* orow = o + (size_t)row * DMODEL;
    for (int i = 0; i < 6; ++i) {
        int c = i * 128 + lane * 2;
        float2 gg = *(const float2*)(g + c);
        float2 bb = *(const float2*)(bta + c);
        float y0 = (vals[2 * i] - mu) * rstd * gg.x + bb.x;
        float y1 = (vals[2 * i + 1] - mu) * rstd * gg.y + bb.y;
        *(unsigned*)(orow + c) = (unsigned)f2bf(y0) | ((unsigned)f2bf(y1) << 16);
    }
}

// ---- GEMM: C[M,768] = epi(A_bf16[M,K] @ W_f32[K,768]); W transposed in LDS -
// 128x128 tile, 4 waves (2x2), each wave 64x64 = 4x4 MFMA 16x16x32 frags.
__global__ __launch_bounds__(256) void gemm_aw(
    const u16* A, const float* W, float* Cf, u16* Cb,
    const float* bias, const float* resid,
    int M, int K, int lda, int ldw, float scale, int do_gelu) {
    __shared__ __align__(16) u16 aT[128 * 32];
    __shared__ __align__(16) u16 bT[128 * 32];
    int tid = threadIdx.x;
    int w = tid >> 6, lane = tid & 63;
    int wm = w >> 1, wn = w & 1;
    int lrow = lane & 15, lq = lane >> 4;
    int row0 = blockIdx.x * 128, col0 = blockIdx.y * 128;

    // A staging map: each thread 2 rows x 8 cols (uint4 of bf16)
    int srow = tid >> 2;         // 0..63
    int skk = (tid & 3) * 8;     // 0,8,16,24
    int arow0 = row0 + srow;       if (arow0 > M - 1) arow0 = M - 1;
    int arow1 = row0 + 64 + srow;  if (arow1 > M - 1) arow1 = M - 1;
    const u16* aP0 = A + (size_t)arow0 * lda + skk;
    const u16* aP1 = A + (size_t)arow1 * lda + skk;
    u16* aL0 = aT + srow * 32 + skk;
    u16* aL1 = aT + (64 + srow) * 32 + skk;
    // W staging map: thread loads k-row (tid>>3), 4 chunks of float4
    int kr = tid >> 3;           // 0..31
    int tc = (tid & 7) * 4;      // 0,4,...,28

    f32x4 acc[4][4];
    const f32x4 zf = {0.f, 0.f, 0.f, 0.f};
    for (int i = 0; i < 4; ++i)
        for (int j = 0; j < 4; ++j) acc[i][j] = zf;

    for (int k0 = 0; k0 < K; k0 += 32) {
        uint4 a0 = *(const uint4*)(aP0 + k0);
        uint4 a1 = *(const uint4*)(aP1 + k0);
        float4 wv0 = *(const float4*)(W + (size_t)(k0 + kr) * ldw + col0 + tc);
        float4 wv1 = *(const float4*)(W + (size_t)(k0 + kr) * ldw + col0 + tc + 32);
        float4 wv2 = *(const float4*)(W + (size_t)(k0 + kr) * ldw + col0 + tc + 64);
        float4 wv3 = *(const float4*)(W + (size_t)(k0 + kr) * ldw + col0 + tc + 96);
        __syncthreads();
        *(uint4*)aL0 = a0; *(uint4*)aL1 = a1;
        bT[(tc + 0) * 32 + kr]  = f2bf(wv0.x); bT[(tc + 1) * 32 + kr]  = f2bf(wv0.y);
        bT[(tc + 2) * 32 + kr]  = f2bf(wv0.z); bT[(tc + 3) * 32 + kr]  = f2bf(wv0.w);
        bT[(tc + 32) * 32 + kr] = f2bf(wv1.x); bT[(tc + 33) * 32 + kr] = f2bf(wv1.y);
        bT[(tc + 34) * 32 + kr] = f2bf(wv1.z); bT[(tc + 35) * 32 + kr] = f2bf(wv1.w);
        bT[(tc + 64) * 32 + kr] = f2bf(wv2.x); bT[(tc + 65) * 32 + kr] = f2bf(wv2.y);
        bT[(tc + 66) * 32 + kr] = f2bf(wv2.z); bT[(tc + 67) * 32 + kr] = f2bf(wv2.w);
        bT[(tc + 96) * 32 + kr] = f2bf(wv3.x); bT[(tc + 97) * 32 + kr] = f2bf(wv3.y);
        bT[(tc + 98) * 32 + kr] = f2bf(wv3.z); bT[(tc + 99) * 32 + kr] = f2bf(wv3.w);
        __syncthreads();
        bf16x8 af[4], bfr[4];
        for (int mt = 0; mt < 4; ++mt)
            af[mt] = *(const bf16x8*)(aT + (wm * 64 + mt * 16 + lrow) * 32 + lq * 8);
        for (int nt = 0; nt < 4; ++nt)
            bfr[nt] = *(const bf16x8*)(bT + (wn * 64 + nt * 16 + lrow) * 32 + lq * 8);
        for (int mt = 0; mt < 4; ++mt)
            for (int nt = 0; nt < 4; ++nt)
                acc[mt][nt] = __builtin_amdgcn_mfma_f32_16x16x32_bf16(af[mt], bfr[nt], acc[mt][nt], 0, 0, 0);
    }

    for (int mt = 0; mt < 4; ++mt) {
        int gmb = row0 + wm * 64 + mt * 16 + lq * 4;
        for (int nt = 0; nt < 4; ++nt) {
            int gc = col0 + wn * 64 + nt * 16 + lrow;
            float bv = bias ? bias[gc] : 0.f;
            for (int r = 0; r < 4; ++r) {
                int gm = gmb + r;
                if (gm < M) {
                    float v0 = (acc[mt][nt][r] + bv) * scale;
                    if (do_gelu) v0 = 0.5f * v0 * (1.f + erff(v0 * 0.70710678118654752f));
                    if (resid) v0 += resid[(size_t)gm * DMODEL + gc];
                    if (Cf) Cf[(size_t)gm * DMODEL + gc] = v0;
                    if (Cb) Cb[(size_t)gm * DMODEL + gc] = f2bf(v0);
                }
            }
        }
    }
}

// ------- attention scores + softmax: q,k fp32 -> probs fp32 -----------------
// grid = (B*H)*4 blocks; block = 4 waves; wave handles mtile = (bid&3)*4 + w
__global__ __launch_bounds__(256) void attn_scores(const float* q,
                                                   const float* k,
                                                   float* attn) {
    __shared__ float S[4][16 * 208];
    __shared__ float mxs[4][16];
    __shared__ float rls[4][16];
    int bid = blockIdx.x;
    int bh = bid >> 2, mb = bid & 3;
    int b = bh / NHEAD, hh = bh - b * NHEAD;
    int tid = threadIdx.x, w = tid >> 6, lane = tid & 63;
    int lrow = lane & 15, lq = lane >> 4;
    int mtile = mb * 4 + w;   // 0..15, valid < 13

    if (mtile < 13) {
        int gm = mtile * 16 + lrow; if (gm > 196) gm = 196;
        const float* qrow = q + (size_t)(b * NSEQ + gm) * DMODEL + hh * 64;
        bf16x8 aq0 = cvt8(qrow + lq * 8);
        bf16x8 aq1 = cvt8(qrow + 32 + lq * 8);
        for (int nt = 0; nt < 13; ++nt) {
            int gn = nt * 16 + lrow; if (gn > 196) gn = 196;
            const float* krow = k + (size_t)(b * NSEQ + gn) * DMODEL + hh * 64;
            bf16x8 bk0 = cvt8(krow + lq * 8);
            bf16x8 bk1 = cvt8(krow + 32 + lq * 8);
            f32x4 a = {0.f, 0.f, 0.f, 0.f};
            a = __builtin_amdgcn_mfma_f32_16x16x32_bf16(aq0, bk0, a, 0, 0, 0);
            a = __builtin_amdgcn_mfma_f32_16x16x32_bf16(aq1, bk1, a, 0, 0, 0);
            for (int r = 0; r < 4; ++r)
                S[w][(lq * 4 + r) * 208 + nt * 16 + lrow] = a[r];
        }
    }
    __syncthreads();
    if (mtile < 13) {
        int r = lane >> 2, c0 = lane & 3;
        int gm = mtile * 16 + r;
        float mx = -1e30f, sm = 0.f;
        if (gm < 197)
            for (int c = c0; c < 197; c += 4) mx = fmaxf(mx, S[w][r * 208 + c]);
        mx = fmaxf(mx, __shfl_xor(mx, 1, 64));
        mx = fmaxf(mx, __shfl_xor(mx, 2, 64));
        if (gm < 197)
            for (int c = c0; c < 197; c += 4) sm += __expf(S[w][r * 208 + c] - mx);
        sm += __shfl_xor(sm, 1, 64);
        sm += __shfl_xor(sm, 2, 64);
        if ((lane & 3) == 0) { mxs[w][r] = mx; rls[w][r] = 1.f / sm; }
    }
    __syncthreads();
    if (mtile < 13) {
        size_t base = (size_t)(b * NHEAD + hh) * (NSEQ * NSEQ);
        for (int it = 0; it < 50; ++it) {
            int idx = it * 64 + lane;   // over 16*197 = 3152
            if (idx < 3152) {
                int row = idx / 197;
                int col = idx - row * 197;
                int gm = mtile * 16 + row;
                if (gm < 197) {
                    float p = __expf(S[w][row * 208 + col] - mxs[w][row]) * rls[w][row];
                    attn[base + (size_t)gm * 197 + col] = p;
                }
            }
        }
    }
}

// ------- PV: probs fp32 @ v bf16 -> out0 fp32 + bf16 copy to ws -------------
__global__ __launch_bounds__(256) void attn_pv(const float* attn,
                                               const u16* v,
                                               float* outf, u16* outb) {
    __shared__ __align__(16) u16 vT[64 * 224];
    __shared__ __align__(16) u16 P[4][16 * 224];
    int bh = blockIdx.x;
    int b = bh / NHEAD, hh = bh - b * NHEAD;
    int tid = threadIdx.x, w = tid >> 6, lane = tid & 63;
    int lrow = lane & 15, lq = lane >> 4;
    // stage V^T [64 cols][224 k] zero-padded; v is bf16 [12608][768]
    {
        int cg = (tid & 7) * 8;
        int rb = tid >> 3;
        for (int i = 0; i < 7; ++i) {
            int r = rb + i * 32;
            union { uint4 q; u16 s[8]; } tmp;
            if (r < 197) {
                tmp.q = *(const uint4*)(v + (size_t)(b * NSEQ + r) * DMODEL + hh * 64 + cg);
            } else {
                tmp.q.x = tmp.q.y = tmp.q.z = tmp.q.w = 0u;
            }
            for (int j = 0; j < 8; ++j) vT[(cg + j) * 224 + r] = tmp.s[j];
        }
    }
    __syncthreads();
    size_t pbase = (size_t)(b * NHEAD + hh) * (NSEQ * NSEQ);
    const f32x4 zf = {0.f, 0.f, 0.f, 0.f};
    for (int it = 0; it < 4; ++it) {
        int mtile = w + it * 4;
        bool valid = (mtile < 13);
        if (valid) {
            for (int ii = 0; ii < 56; ++ii) {     // 16*224 = 3584
                int idx = ii * 64 + lane;
                int row = idx / 224;
                int col = idx - row * 224;
                u16 val = 0;
                if (col < 197) {
                    int gm = mtile * 16 + row; if (gm > 196) gm = 196;
                    val = f2bf(attn[pbase + (size_t)gm * 197 + col]);
                }
                P[w][idx] = val;
            }
        }
        __syncthreads();   // fence + wait: P writes visible
        if (valid) {
            f32x4 acc[4];
            for (int nt = 0; nt < 4; ++nt) acc[nt] = zf;
            for (int ks = 0; ks < 7; ++ks) {
                bf16x8 af = *(const bf16x8*)(&P[w][lrow * 224 + ks * 32 + lq * 8]);
                for (int nt = 0; nt < 4; ++nt) {
                    bf16x8 bv = *(const bf16x8*)(&vT[(nt * 16 + lrow) * 224 + ks * 32 + lq * 8]);
                    acc[nt] = __builtin_amdgcn_mfma_f32_16x16x32_bf16(af, bv, acc[nt], 0, 0, 0);
                }
            }
            for (int nt = 0; nt < 4; ++nt) {
                int gcol = hh * 64 + nt * 16 + lrow;
                for (int r = 0; r < 4; ++r) {
                    int gm = mtile * 16 + lq * 4 + r;
                    if (gm < 197) {
                        size_t off = (size_t)(b * NSEQ + gm) * DMODEL + gcol;
                        outf[off] = acc[nt][r];
                        outb[off] = f2bf(acc[nt][r]);
                    }
                }
            }
        }
        __syncthreads();   // protect P reuse next iteration
    }
}

extern "C" void kernel_launch(void* const* d_in, const int* in_sizes, int n_in,
                              void* d_out, int out_size, void* d_ws, size_t ws_size,
                              hipStream_t stream) {
    const float* x    = (const float*)d_in[0];
    const float* ln1g = (const float*)d_in[1];
    const float* ln1b = (const float*)d_in[2];
    const float* wq   = (const float*)d_in[3];
    const float* bq   = (const float*)d_in[4];
    const float* wk   = (const float*)d_in[5];
    const float* bk   = (const float*)d_in[6];
    const float* wv   = (const float*)d_in[7];
    const float* bv   = (const float*)d_in[8];
    const float* wo   = (const float*)d_in[9];
    const float* bo   = (const float*)d_in[10];
    const float* ln2g = (const float*)d_in[11];
    const float* ln2b = (const float*)d_in[12];
    const float* w1   = (const float*)d_in[13];
    const float* b1   = (const float*)d_in[14];
    const float* w2   = (const float*)d_in[15];
    const float* b2   = (const float*)d_in[16];

    float* out     = (float*)d_out;
    float* preproj = out;                 // output 0: 12608*768 = 9,682,944 fp32
    float* hidden  = out + 9682944;       // output 1: 12608*768 fp32
    float* attnw   = out + 19365888;      // output 2: 64*12*197*197 = 29,805,312 fp32

    // workspace: two bf16 buffers, 36.9 MB total
    u16* bufA = (u16*)d_ws;               // h -> attn_out(bf16) -> hsn
    u16* bufB = bufA + 9682944;           // v -> gelu-quarter

    // LN1: x -> bufA (bf16)
    ln_rows<<<3152, 256, 0, stream>>>(x, ln1g, ln1b, bufA, MROWS);
    // QKV: q(fp32,scaled)->out0, k(fp32)->out1, v(bf16)->bufB
    gemm_aw<<<dim3(99, 6), 256, 0, stream>>>(bufA, wq, preproj, nullptr, bq, nullptr,
                                             MROWS, 768, 768, 768, 0.125f, 0);
    gemm_aw<<<dim3(99, 6), 256, 0, stream>>>(bufA, wk, hidden, nullptr, bk, nullptr,
                                             MROWS, 768, 768, 768, 1.f, 0);
    gemm_aw<<<dim3(99, 6), 256, 0, stream>>>(bufA, wv, nullptr, bufB, bv, nullptr,
                                             MROWS, 768, 768, 768, 1.f, 0);
    // attention: probs fp32 -> attnw (output 2)
    attn_scores<<<3072, 256, 0, stream>>>(preproj, hidden, attnw);
    // PV: -> out0 fp32 (final output 0) + bf16 copy into bufA (h dead)
    attn_pv<<<768, 256, 0, stream>>>(attnw, bufB, preproj, bufA);
    // out-proj + residual(x) -> hidden (fp32 hs); k dead
    gemm_aw<<<dim3(99, 6), 256, 0, stream>>>(bufA, wo, hidden, nullptr, bo, x,
                                             MROWS, 768, 768, 768, 1.f, 0);
    // LN2: hidden -> bufA (bf16 hsn)
    ln_rows<<<3152, 256, 0, stream>>>(hidden, ln2g, ln2b, bufA, MROWS);
    // MLP in 4 K-quarters of DFF; gelu quarter (bf16) in bufB (v dead)
    for (int qi = 0; qi < 4; ++qi) {
        gemm_aw<<<dim3(99, 6), 256, 0, stream>>>(
            bufA, w1 + qi * 768, nullptr, bufB, b1 + qi * 768, nullptr,
            MROWS, 768, 768, 3072, 1.f, 1);
        gemm_aw<<<dim3(99, 6), 256, 0, stream>>>(
            bufB, w2 + (size_t)qi * 768 * 768, hidden, nullptr,
            (qi == 0) ? b2 : nullptr, hidden,
            MROWS, 768, 768, 768, 1.f, 0);
    }
}